// Round 1
// baseline (1105.500 us; speedup 1.0000x reference)
//
#include <hip/hip_runtime.h>
#include <math.h>

// Problem constants
#define B_  4
#define C_  256
#define N_  4096
#define CK_ 32
#define CV_ 128

static constexpr float LOG2E = 1.4426950408889634f;

// ---------------------------------------------------------------------------
// Kernel 1: fused projections. theta/phi/g = W @ x + b  (per-pixel 1x1 conv)
// Grid: (N/1024, 192/8, B); block 256. Each block: 8 output rows x 1024 cols.
// ---------------------------------------------------------------------------
__global__ __launch_bounds__(256) void proj_kernel(
    const float* __restrict__ x,
    const float* __restrict__ theta_w, const float* __restrict__ theta_b,
    const float* __restrict__ phi_w,   const float* __restrict__ phi_b,
    const float* __restrict__ g_w,     const float* __restrict__ g_b,
    float* __restrict__ theta, float* __restrict__ phi, float* __restrict__ g)
{
    const int b  = blockIdx.z;
    const int o0 = blockIdx.y * 8;                 // 0..184
    const int nb = blockIdx.x * 1024 + threadIdx.x * 4;

    const float* wsrc; const float* bsrc; float* dst; int orow; int rows;
    if (o0 < 32)      { wsrc = theta_w; bsrc = theta_b; dst = theta; orow = o0;      rows = 32;  }
    else if (o0 < 64) { wsrc = phi_w;   bsrc = phi_b;   dst = phi;   orow = o0 - 32; rows = 32;  }
    else              { wsrc = g_w;     bsrc = g_b;     dst = g;     orow = o0 - 64; rows = 128; }

    __shared__ float wl[8][C_];
    #pragma unroll
    for (int k = 0; k < 8; ++k)
        wl[k][threadIdx.x] = wsrc[(orow + k) * C_ + threadIdx.x];
    __syncthreads();

    const float* xb = x + (size_t)b * C_ * N_ + nb;
    float4 acc[8];
    #pragma unroll
    for (int k = 0; k < 8; ++k) acc[k] = make_float4(0.f, 0.f, 0.f, 0.f);

    for (int c = 0; c < C_; ++c) {
        const float4 xv = *(const float4*)(xb + (size_t)c * N_);
        #pragma unroll
        for (int k = 0; k < 8; ++k) {
            const float w = wl[k][c];
            acc[k].x += w * xv.x; acc[k].y += w * xv.y;
            acc[k].z += w * xv.z; acc[k].w += w * xv.w;
        }
    }
    #pragma unroll
    for (int k = 0; k < 8; ++k) {
        const float bias = bsrc[orow + k];
        float4 v = acc[k];
        v.x += bias; v.y += bias; v.z += bias; v.w += bias;
        *(float4*)(dst + ((size_t)b * rows + orow + k) * N_ + nb) = v;
    }
}

// ---------------------------------------------------------------------------
// Kernel 2: column stats. Z[b][j] = sum_i exp2( log2e * theta[:,i].phi[:,j] )
// Each thread owns one j (phi column in regs, log2e prefolded); theta reads
// are block-uniform -> scalar loads. Grid: (N/256, 4 i-chunks, B).
// Partial sums combined with atomicAdd (Z zeroed by hipMemsetAsync).
// ---------------------------------------------------------------------------
__global__ __launch_bounds__(256) void colstats_kernel(
    const float* __restrict__ theta, const float* __restrict__ phi,
    float* __restrict__ Z)
{
    const int b = blockIdx.z;
    const int j = blockIdx.x * 256 + threadIdx.x;
    const int i0 = blockIdx.y * (N_ / 4);

    float phr[CK_];
    #pragma unroll
    for (int c = 0; c < CK_; ++c)
        phr[c] = phi[((size_t)b * CK_ + c) * N_ + j] * LOG2E;

    const float* th = theta + (size_t)b * CK_ * N_;
    float zsum = 0.f;
    for (int i = i0; i < i0 + N_ / 4; i += 4) {
        float s0 = 0.f, s1 = 0.f, s2 = 0.f, s3 = 0.f;
        #pragma unroll
        for (int c = 0; c < CK_; ++c) {
            const float4 tv = *(const float4*)(th + (size_t)c * N_ + i);
            s0 += tv.x * phr[c]; s1 += tv.y * phr[c];
            s2 += tv.z * phr[c]; s3 += tv.w * phr[c];
        }
        zsum += exp2f(s0) + exp2f(s1) + exp2f(s2) + exp2f(s3);
    }
    atomicAdd(&Z[(size_t)b * N_ + j], zsum);
}

// ---------------------------------------------------------------------------
// Kernel 3: fold normalizer into g:  g[b][c][n] /= Z[b][n]
// ---------------------------------------------------------------------------
__global__ __launch_bounds__(256) void gscale_kernel(
    float* __restrict__ g, const float* __restrict__ Z)
{
    const size_t idx = ((size_t)blockIdx.x * 256 + threadIdx.x) * 4;
    const int n = (int)(idx & (N_ - 1));
    const int b = (int)(idx / ((size_t)CV_ * N_));
    float4 gv = *(float4*)(g + idx);
    const float4 zv = *(const float4*)(Z + (size_t)b * N_ + n);
    gv.x /= zv.x; gv.y /= zv.y; gv.z /= zv.z; gv.w /= zv.w;
    *(float4*)(g + idx) = gv;
}

// ---------------------------------------------------------------------------
// Kernel 4: o_pre[b][c][i] = sum_j gp[c][j] * exp2( log2e * theta[:,i].phi[:,j] )
// Block: (b, 32-wide i-tile), loops j in tiles of 32. Register-blocked 4x4.
// gl rows padded to 36 floats to avoid 8-way bank conflicts on column reads.
// ---------------------------------------------------------------------------
__global__ __launch_bounds__(256) void opre_kernel(
    const float* __restrict__ theta, const float* __restrict__ phi,
    const float* __restrict__ g, float* __restrict__ o_pre)
{
    const int b  = blockIdx.y;
    const int i0 = blockIdx.x * 32;
    const int tid = threadIdx.x;

    __shared__ float ph[CK_][32];      // phi tile [c][jj]
    __shared__ float El[32][32];       // E[jj][ii]
    __shared__ float gl[CV_][36];      // gp tile [c][jj], padded stride

    // E-phase mapping: this thread computes E[jb..jb+3][ii]
    const int ii = tid & 31;
    const int jb = (tid >> 5) * 4;
    // theta fragment (log2e prefolded), loop-invariant over j-tiles
    float thr[CK_];
    #pragma unroll
    for (int c = 0; c < CK_; ++c)
        thr[c] = theta[((size_t)b * CK_ + c) * N_ + i0 + ii] * LOG2E;

    // accumulate-phase mapping: 4 c's x 4 i's per thread
    const int c0  = (tid >> 3) * 4;
    const int it0 = (tid & 7) * 4;
    float acc[4][4];
    #pragma unroll
    for (int cc = 0; cc < 4; ++cc)
        #pragma unroll
        for (int k = 0; k < 4; ++k) acc[cc][k] = 0.f;

    for (int j0 = 0; j0 < N_; j0 += 32) {
        __syncthreads();   // previous iteration's reads of ph/gl/El done
        #pragma unroll
        for (int r = 0; r < 4; ++r) {            // CK_*32/256 = 4
            const int idx = r * 256 + tid;
            const int c = idx >> 5, jj = idx & 31;
            ph[c][jj] = phi[((size_t)b * CK_ + c) * N_ + j0 + jj];
        }
        #pragma unroll
        for (int r = 0; r < 16; ++r) {           // CV_*32/256 = 16
            const int idx = r * 256 + tid;
            const int c = idx >> 5, jj = idx & 31;
            gl[c][jj] = g[((size_t)b * CV_ + c) * N_ + j0 + jj];
        }
        __syncthreads();

        // score + exp phase
        {
            float s0 = 0.f, s1 = 0.f, s2 = 0.f, s3 = 0.f;
            #pragma unroll
            for (int c = 0; c < CK_; ++c) {
                const float4 pv = *(const float4*)&ph[c][jb];
                const float t = thr[c];
                s0 += t * pv.x; s1 += t * pv.y; s2 += t * pv.z; s3 += t * pv.w;
            }
            El[jb + 0][ii] = exp2f(s0);
            El[jb + 1][ii] = exp2f(s1);
            El[jb + 2][ii] = exp2f(s2);
            El[jb + 3][ii] = exp2f(s3);
        }
        __syncthreads();

        // accumulate phase: acc[c][i] += sum_j gl[c][j] * El[j][i]
        #pragma unroll
        for (int jc = 0; jc < 32; jc += 4) {
            const float4 e0 = *(const float4*)&El[jc + 0][it0];
            const float4 e1 = *(const float4*)&El[jc + 1][it0];
            const float4 e2 = *(const float4*)&El[jc + 2][it0];
            const float4 e3 = *(const float4*)&El[jc + 3][it0];
            #pragma unroll
            for (int cc = 0; cc < 4; ++cc) {
                const float4 gv = *(const float4*)&gl[c0 + cc][jc];
                acc[cc][0] += gv.x * e0.x + gv.y * e1.x + gv.z * e2.x + gv.w * e3.x;
                acc[cc][1] += gv.x * e0.y + gv.y * e1.y + gv.z * e2.y + gv.w * e3.y;
                acc[cc][2] += gv.x * e0.z + gv.y * e1.z + gv.z * e2.z + gv.w * e3.z;
                acc[cc][3] += gv.x * e0.w + gv.y * e1.w + gv.z * e2.w + gv.w * e3.w;
            }
        }
    }

    #pragma unroll
    for (int cc = 0; cc < 4; ++cc) {
        float4 v = make_float4(acc[cc][0], acc[cc][1], acc[cc][2], acc[cc][3]);
        *(float4*)(o_pre + ((size_t)b * CV_ + c0 + cc) * N_ + i0 + it0) = v;
    }
}

// ---------------------------------------------------------------------------
// Kernel 5: out = x + gamma * (o_w @ o_pre + o_b)
// Grid: (N/1024, C/8, B); block 256.
// ---------------------------------------------------------------------------
__global__ __launch_bounds__(256) void final_kernel(
    const float* __restrict__ o_pre, const float* __restrict__ o_w,
    const float* __restrict__ o_b,  const float* __restrict__ gamma,
    const float* __restrict__ x, float* __restrict__ out)
{
    const int b  = blockIdx.z;
    const int oc = blockIdx.y * 8;
    const int nb = blockIdx.x * 1024 + threadIdx.x * 4;

    __shared__ float wl[8][CV_];
    #pragma unroll
    for (int r = 0; r < 4; ++r) {                // 8*128/256 = 4
        const int idx = r * 256 + threadIdx.x;
        const int k = idx >> 7, c = idx & 127;
        wl[k][c] = o_w[(oc + k) * CV_ + c];
    }
    __syncthreads();

    const float* pb = o_pre + (size_t)b * CV_ * N_ + nb;
    float4 acc[8];
    #pragma unroll
    for (int k = 0; k < 8; ++k) acc[k] = make_float4(0.f, 0.f, 0.f, 0.f);

    for (int c = 0; c < CV_; ++c) {
        const float4 pv = *(const float4*)(pb + (size_t)c * N_);
        #pragma unroll
        for (int k = 0; k < 8; ++k) {
            const float w = wl[k][c];
            acc[k].x += w * pv.x; acc[k].y += w * pv.y;
            acc[k].z += w * pv.z; acc[k].w += w * pv.w;
        }
    }

    const float gm = gamma[0];
    #pragma unroll
    for (int k = 0; k < 8; ++k) {
        const size_t off = ((size_t)b * C_ + oc + k) * N_ + nb;
        const float4 xv = *(const float4*)(x + off);
        const float bias = o_b[oc + k];
        float4 v;
        v.x = xv.x + gm * (acc[k].x + bias);
        v.y = xv.y + gm * (acc[k].y + bias);
        v.z = xv.z + gm * (acc[k].z + bias);
        v.w = xv.w + gm * (acc[k].w + bias);
        *(float4*)(out + off) = v;
    }
}

// ---------------------------------------------------------------------------
extern "C" void kernel_launch(void* const* d_in, const int* in_sizes, int n_in,
                              void* d_out, int out_size, void* d_ws, size_t ws_size,
                              hipStream_t stream)
{
    const float* x       = (const float*)d_in[0];
    const float* theta_w = (const float*)d_in[1];
    const float* theta_b = (const float*)d_in[2];
    const float* phi_w   = (const float*)d_in[3];
    const float* phi_b   = (const float*)d_in[4];
    const float* g_w     = (const float*)d_in[5];
    const float* g_b     = (const float*)d_in[6];
    const float* o_w     = (const float*)d_in[7];
    const float* o_b     = (const float*)d_in[8];
    const float* gamma   = (const float*)d_in[9];
    float* out = (float*)d_out;

    float* ws    = (float*)d_ws;
    float* theta = ws;                               // B*CK*N
    float* phi   = theta + (size_t)B_ * CK_ * N_;    // B*CK*N
    float* g     = phi   + (size_t)B_ * CK_ * N_;    // B*CV*N
    float* Z     = g     + (size_t)B_ * CV_ * N_;    // B*N
    float* o_pre = Z     + (size_t)B_ * N_;          // B*CV*N

    hipMemsetAsync(Z, 0, (size_t)B_ * N_ * sizeof(float), stream);

    proj_kernel<<<dim3(4, 24, B_), 256, 0, stream>>>(
        x, theta_w, theta_b, phi_w, phi_b, g_w, g_b, theta, phi, g);
    colstats_kernel<<<dim3(16, 4, B_), 256, 0, stream>>>(theta, phi, Z);
    gscale_kernel<<<dim3((B_ * CV_ * N_) / 1024), 256, 0, stream>>>(g, Z);
    opre_kernel<<<dim3(N_ / 32, B_), 256, 0, stream>>>(theta, phi, g, o_pre);
    final_kernel<<<dim3(4, 32, B_), 256, 0, stream>>>(o_pre, o_w, o_b, gamma, x, out);
}

// Round 2
// 285.291 us; speedup vs baseline: 3.8750x; 3.8750x over previous
//
#include <hip/hip_runtime.h>
#include <math.h>

// Problem constants
#define B_  4
#define C_  256
#define N_  4096
#define CK_ 32
#define CV_ 128

typedef __attribute__((ext_vector_type(8))) short short8;  // 8 bf16 = 4 VGPRs (MFMA A/B frag)
typedef __attribute__((ext_vector_type(4))) float f32x4;   // MFMA C/D frag
typedef unsigned short u16;
typedef unsigned int   u32;

static constexpr float LOG2E = 1.4426950408889634f;

static __device__ __forceinline__ u16 f2bf(float f) {       // fp32 -> bf16 RNE
    u32 u = __float_as_uint(f);
    u = (u + 0x7FFFu + ((u >> 16) & 1u)) >> 16;
    return (u16)u;
}
static __device__ __forceinline__ float bf2f(u16 h) {       // exact
    return __uint_as_float(((u32)h) << 16);
}

// ---------------------------------------------------------------------------
// Kernel 1: projections (fp32 compute). Emits:
//   theta_t [B][N][32] bf16, value = (theta+bias)*log2e  (A-frag friendly, k-contig)
//   phi_t   [B][N][32] bf16                               (B-frag friendly)
//   g16     [B][CV][N] bf16                               (PV A-frag friendly)
// Grid (4, 24, B), block 256: 8 out-rows x 1024 cols per block.
// ---------------------------------------------------------------------------
__global__ __launch_bounds__(256) void proj_kernel(
    const float* __restrict__ x,
    const float* __restrict__ theta_w, const float* __restrict__ theta_b,
    const float* __restrict__ phi_w,   const float* __restrict__ phi_b,
    const float* __restrict__ g_w,     const float* __restrict__ g_b,
    u16* __restrict__ theta_t, u16* __restrict__ phi_t, u16* __restrict__ g16)
{
    const int b  = blockIdx.z;
    const int o0 = blockIdx.y * 8;                 // 0..184
    const int nb = blockIdx.x * 1024 + threadIdx.x * 4;

    const float* wsrc; const float* bsrc; int orow;
    if (o0 < 32)      { wsrc = theta_w; bsrc = theta_b; orow = o0; }
    else if (o0 < 64) { wsrc = phi_w;   bsrc = phi_b;   orow = o0 - 32; }
    else              { wsrc = g_w;     bsrc = g_b;     orow = o0 - 64; }

    __shared__ float wl[8][C_];
    #pragma unroll
    for (int k = 0; k < 8; ++k)
        wl[k][threadIdx.x] = wsrc[(orow + k) * C_ + threadIdx.x];
    __syncthreads();

    const float* xb = x + (size_t)b * C_ * N_ + nb;
    float4 acc[8];
    #pragma unroll
    for (int k = 0; k < 8; ++k) acc[k] = make_float4(0.f, 0.f, 0.f, 0.f);

    for (int c = 0; c < C_; ++c) {
        const float4 xv = *(const float4*)(xb + (size_t)c * N_);
        #pragma unroll
        for (int k = 0; k < 8; ++k) {
            const float w = wl[k][c];
            acc[k].x += w * xv.x; acc[k].y += w * xv.y;
            acc[k].z += w * xv.z; acc[k].w += w * xv.w;
        }
    }

    float bias[8];
    #pragma unroll
    for (int k = 0; k < 8; ++k) bias[k] = bsrc[orow + k];

    if (o0 < 64) {
        // transposed bf16 store: 4 n-rows x 8 contiguous c = 16 B each
        u16* dst = (o0 < 32) ? theta_t : phi_t;
        const float scale = (o0 < 32) ? LOG2E : 1.0f;
        #pragma unroll
        for (int v = 0; v < 4; ++v) {
            union { u16 us[8]; uint4 u4; } pk;
            #pragma unroll
            for (int k = 0; k < 8; ++k)
                pk.us[k] = f2bf((((const float*)&acc[k])[v] + bias[k]) * scale);
            *(uint4*)(dst + (size_t)(b * N_ + nb + v) * CK_ + orow) = pk.u4;
        }
    } else {
        // g: row-major bf16 [c][n], 4 n per row = 8 B store
        #pragma unroll
        for (int k = 0; k < 8; ++k) {
            union { u16 us[4]; uint2 u2; } pk;
            pk.us[0] = f2bf(acc[k].x + bias[k]);
            pk.us[1] = f2bf(acc[k].y + bias[k]);
            pk.us[2] = f2bf(acc[k].z + bias[k]);
            pk.us[3] = f2bf(acc[k].w + bias[k]);
            *(uint2*)(g16 + (size_t)(b * CV_ + orow + k) * N_ + nb) = pk.u2;
        }
    }
}

// ---------------------------------------------------------------------------
// Kernel 2: Z[b][j] = sum_i exp2(S[i][j]) via MFMA 16x16x32 (K=32=CK, 1 instr).
// Grid (N/32, 4 i-strips, B), block 256. Wave: j-half (w&1), i-phase (w>>1).
// D layout: col(j)=lane&15, row(i)=quad*4+reg — per-lane colsum, xor-reduce.
// ---------------------------------------------------------------------------
__global__ __launch_bounds__(256) void colstats_kernel(
    const u16* __restrict__ theta_t, const u16* __restrict__ phi_t,
    float* __restrict__ Z)
{
    const int b  = blockIdx.z;
    const int j0 = blockIdx.x * 32;
    const int istart = blockIdx.y * (N_ / 4);
    const int tid = threadIdx.x;
    const int wave = tid >> 6, lane = tid & 63;
    const int lr = lane & 15, q = lane >> 4;

    const int jW = j0 + (wave & 1) * 16;
    const short8 bF = *(const short8*)(phi_t + (size_t)(b * N_ + jW + lr) * CK_ + q * 8);

    const u16* thp = theta_t + (size_t)b * N_ * CK_;
    const f32x4 zero = {0.f, 0.f, 0.f, 0.f};
    float zacc = 0.f;
    for (int it = istart + (wave >> 1) * 16; it < istart + N_ / 4; it += 32) {
        const short8 aF = *(const short8*)(thp + (size_t)(it + lr) * CK_ + q * 8);
        f32x4 S = __builtin_amdgcn_mfma_f32_16x16x32_bf16(aF, bF, zero, 0, 0, 0);
        zacc += exp2f(S[0]) + exp2f(S[1]) + exp2f(S[2]) + exp2f(S[3]);
    }
    zacc += __shfl_xor(zacc, 16);
    zacc += __shfl_xor(zacc, 32);
    if (lane < 16) atomicAdd(&Z[(size_t)b * N_ + jW + lr], zacc);
}

// ---------------------------------------------------------------------------
// Kernel 3: fold 1/Z into g (in place, bf16). 8 elems/thread.
// ---------------------------------------------------------------------------
__global__ __launch_bounds__(256) void gscale_kernel(
    u16* __restrict__ g16, const float* __restrict__ Z)
{
    const size_t idx = ((size_t)blockIdx.x * 256 + threadIdx.x) * 8;
    const int n = (int)(idx & (N_ - 1));
    const int b = (int)(idx / ((size_t)CV_ * N_));
    uint4 raw = *(const uint4*)(g16 + idx);
    const float4 z0 = *(const float4*)(Z + (size_t)b * N_ + n);
    const float4 z1 = *(const float4*)(Z + (size_t)b * N_ + n + 4);
    const float zz[8] = {z0.x, z0.y, z0.z, z0.w, z1.x, z1.y, z1.z, z1.w};
    u16* pr = (u16*)&raw;
    union { u16 us[8]; uint4 u4; } pk;
    #pragma unroll
    for (int k = 0; k < 8; ++k) pk.us[k] = f2bf(bf2f(pr[k]) / zz[k]);
    *(uint4*)(g16 + idx) = pk.u4;
}

// ---------------------------------------------------------------------------
// Kernel 4: o_pre[c][i] = sum_j gp[c][j] * exp2(S[i][j]) — fused MFMA.
// Grid (N/32, B) = 512 blocks, block 256 (4 waves), 2 blocks/CU.
// Per 64-j chunk: S (2 MFMA/wave) -> exp2 -> E bf16 to LDS (XOR-swizzled
// 16B chunks: phys = (c>>3)^(row&7), breaks C->B layout transpose conflicts)
// -> PV (8 MFMA/wave, wave owns 32 c x 32 i).
// ---------------------------------------------------------------------------
__global__ __launch_bounds__(256) void opre_kernel(
    const u16* __restrict__ theta_t, const u16* __restrict__ phi_t,
    const u16* __restrict__ g16, float* __restrict__ o_pre)
{
    const int b  = blockIdx.y;
    const int i0 = blockIdx.x * 32;
    const int tid = threadIdx.x;
    const int wave = tid >> 6, lane = tid & 63;
    const int lr = lane & 15, q = lane >> 4;

    __shared__ u16 El[32 * 64];                     // 4 KB, XOR-swizzled rows

    // S-phase: wave owns j-strip jS = wave*16, all 32 i (2 A-frags, invariant)
    const int jS = wave * 16;
    short8 aF[2];
    #pragma unroll
    for (int ih = 0; ih < 2; ++ih)
        aF[ih] = *(const short8*)(theta_t +
                    (size_t)(b * N_ + i0 + ih * 16 + lr) * CK_ + q * 8);

    // PV-phase: wave owns c-strip cw = wave*32 (2 m-tiles), full 32 i (2 n-tiles)
    const int cw = wave * 32;
    f32x4 acc[2][2];
    #pragma unroll
    for (int mt = 0; mt < 2; ++mt)
        #pragma unroll
        for (int nt = 0; nt < 2; ++nt) acc[mt][nt] = (f32x4){0.f, 0.f, 0.f, 0.f};

    const f32x4 zero = {0.f, 0.f, 0.f, 0.f};
    const int colc = (jS + lr) >> 3;                // logical 16B chunk of this col

    for (int j0 = 0; j0 < N_; j0 += 64) {
        // S = theta^T phi for this chunk (theta pre-scaled by log2e)
        const short8 bF = *(const short8*)(phi_t +
                    (size_t)(b * N_ + j0 + jS + lr) * CK_ + q * 8);
        f32x4 S0 = __builtin_amdgcn_mfma_f32_16x16x32_bf16(aF[0], bF, zero, 0, 0, 0);
        f32x4 S1 = __builtin_amdgcn_mfma_f32_16x16x32_bf16(aF[1], bF, zero, 0, 0, 0);

        // E = exp2(S) -> LDS (bf16), swizzled
        #pragma unroll
        for (int reg = 0; reg < 4; ++reg) {
            const int r0 = q * 4 + reg;
            El[r0 * 64 + (((colc ^ (r0 & 7)) << 3) | (lr & 7))] = f2bf(exp2f(S0[reg]));
            const int r1 = r0 + 16;
            El[r1 * 64 + (((colc ^ (r1 & 7)) << 3) | (lr & 7))] = f2bf(exp2f(S1[reg]));
        }
        __syncthreads();

        // PV: acc[c-tile][i-tile] += gp . E^T
        #pragma unroll
        for (int ks = 0; ks < 2; ++ks) {
            short8 bE[2];
            #pragma unroll
            for (int nt = 0; nt < 2; ++nt) {
                const int row = nt * 16 + lr;
                const int cc  = (ks * 4 + q) ^ (row & 7);
                bE[nt] = *(const short8*)(El + row * 64 + cc * 8);
            }
            #pragma unroll
            for (int mt = 0; mt < 2; ++mt) {
                const short8 aG = *(const short8*)(g16 +
                        (size_t)(b * CV_ + cw + mt * 16 + lr) * N_ + j0 + ks * 32 + q * 8);
                acc[mt][0] = __builtin_amdgcn_mfma_f32_16x16x32_bf16(aG, bE[0], acc[mt][0], 0, 0, 0);
                acc[mt][1] = __builtin_amdgcn_mfma_f32_16x16x32_bf16(aG, bE[1], acc[mt][1], 0, 0, 0);
            }
        }
        __syncthreads();
    }

    // epilogue: D layout col(i)=lane&15, row(c)=quad*4+reg
    #pragma unroll
    for (int mt = 0; mt < 2; ++mt)
        #pragma unroll
        for (int nt = 0; nt < 2; ++nt)
            #pragma unroll
            for (int reg = 0; reg < 4; ++reg)
                o_pre[(size_t)(b * CV_ + cw + mt * 16 + q * 4 + reg) * N_
                      + i0 + nt * 16 + lr] = acc[mt][nt][reg];
}

// ---------------------------------------------------------------------------
// Kernel 5: out = x + gamma * (o_w @ o_pre + o_b)   (unchanged fp32)
// ---------------------------------------------------------------------------
__global__ __launch_bounds__(256) void final_kernel(
    const float* __restrict__ o_pre, const float* __restrict__ o_w,
    const float* __restrict__ o_b,  const float* __restrict__ gamma,
    const float* __restrict__ x, float* __restrict__ out)
{
    const int b  = blockIdx.z;
    const int oc = blockIdx.y * 8;
    const int nb = blockIdx.x * 1024 + threadIdx.x * 4;

    __shared__ float wl[8][CV_];
    #pragma unroll
    for (int r = 0; r < 4; ++r) {
        const int idx = r * 256 + threadIdx.x;
        const int k = idx >> 7, c = idx & 127;
        wl[k][c] = o_w[(oc + k) * CV_ + c];
    }
    __syncthreads();

    const float* pb = o_pre + (size_t)b * CV_ * N_ + nb;
    float4 acc[8];
    #pragma unroll
    for (int k = 0; k < 8; ++k) acc[k] = make_float4(0.f, 0.f, 0.f, 0.f);

    for (int c = 0; c < CV_; ++c) {
        const float4 pv = *(const float4*)(pb + (size_t)c * N_);
        #pragma unroll
        for (int k = 0; k < 8; ++k) {
            const float w = wl[k][c];
            acc[k].x += w * pv.x; acc[k].y += w * pv.y;
            acc[k].z += w * pv.z; acc[k].w += w * pv.w;
        }
    }

    const float gm = gamma[0];
    #pragma unroll
    for (int k = 0; k < 8; ++k) {
        const size_t off = ((size_t)b * C_ + oc + k) * N_ + nb;
        const float4 xv = *(const float4*)(x + off);
        const float bias = o_b[oc + k];
        float4 v;
        v.x = xv.x + gm * (acc[k].x + bias);
        v.y = xv.y + gm * (acc[k].y + bias);
        v.z = xv.z + gm * (acc[k].z + bias);
        v.w = xv.w + gm * (acc[k].w + bias);
        *(float4*)(out + off) = v;
    }
}

// ---------------------------------------------------------------------------
extern "C" void kernel_launch(void* const* d_in, const int* in_sizes, int n_in,
                              void* d_out, int out_size, void* d_ws, size_t ws_size,
                              hipStream_t stream)
{
    const float* x       = (const float*)d_in[0];
    const float* theta_w = (const float*)d_in[1];
    const float* theta_b = (const float*)d_in[2];
    const float* phi_w   = (const float*)d_in[3];
    const float* phi_b   = (const float*)d_in[4];
    const float* g_w     = (const float*)d_in[5];
    const float* g_b     = (const float*)d_in[6];
    const float* o_w     = (const float*)d_in[7];
    const float* o_b     = (const float*)d_in[8];
    const float* gamma   = (const float*)d_in[9];
    float* out = (float*)d_out;

    // workspace: theta_t 1MB | phi_t 1MB | g16 4MB | Z 64KB | o_pre 8MB  (~14MB)
    u16* theta_t = (u16*)d_ws;
    u16* phi_t   = theta_t + (size_t)B_ * N_ * CK_;
    u16* g16     = phi_t   + (size_t)B_ * N_ * CK_;
    float* Z     = (float*)(g16 + (size_t)B_ * CV_ * N_);
    float* o_pre = Z + (size_t)B_ * N_;

    hipMemsetAsync(Z, 0, (size_t)B_ * N_ * sizeof(float), stream);

    proj_kernel<<<dim3(4, 24, B_), 256, 0, stream>>>(
        x, theta_w, theta_b, phi_w, phi_b, g_w, g_b, theta_t, phi_t, g16);
    colstats_kernel<<<dim3(N_ / 32, 4, B_), 256, 0, stream>>>(theta_t, phi_t, Z);
    gscale_kernel<<<dim3((B_ * CV_ * N_) / 2048), 256, 0, stream>>>(g16, Z);
    opre_kernel<<<dim3(N_ / 32, B_), 256, 0, stream>>>(theta_t, phi_t, g16, o_pre);
    final_kernel<<<dim3(4, 32, B_), 256, 0, stream>>>(o_pre, o_w, o_b, gamma, x, out);
}

// Round 3
// 205.372 us; speedup vs baseline: 5.3829x; 1.3891x over previous
//
#include <hip/hip_runtime.h>
#include <math.h>

// Problem constants
#define B_  4
#define C_  256
#define N_  4096
#define CK_ 32
#define CV_ 128

typedef __attribute__((ext_vector_type(8))) short short8;  // 8 bf16 = 4 VGPRs
typedef __attribute__((ext_vector_type(4))) float f32x4;   // MFMA C/D frag
typedef unsigned short u16;
typedef unsigned int   u32;

static constexpr float LOG2E = 1.4426950408889634f;

static __device__ __forceinline__ u16 f2bf(float f) {       // fp32 -> bf16 RNE
    u32 u = __float_as_uint(f);
    u = (u + 0x7FFFu + ((u >> 16) & 1u)) >> 16;
    return (u16)u;
}
static __device__ __forceinline__ float bf2f(u16 h) {
    return __uint_as_float(((u32)h) << 16);
}

// ---------------------------------------------------------------------------
// Kernel 0a: weight convert. W16[192][256] = [theta*log2e; phi; g] bf16,
// ow16[256][128] bf16. 81920 elements, grid 320x256.
// ---------------------------------------------------------------------------
__global__ __launch_bounds__(256) void wconv_kernel(
    const float* __restrict__ theta_w, const float* __restrict__ phi_w,
    const float* __restrict__ g_w,     const float* __restrict__ o_w,
    u16* __restrict__ W16, u16* __restrict__ ow16)
{
    const int idx = blockIdx.x * 256 + threadIdx.x;
    if (idx < 8192)        W16[idx] = f2bf(theta_w[idx] * LOG2E);
    else if (idx < 16384)  W16[idx] = f2bf(phi_w[idx - 8192]);
    else if (idx < 49152)  W16[idx] = f2bf(g_w[idx - 16384]);
    else                   ow16[idx - 49152] = f2bf(o_w[idx - 49152]);
}

// ---------------------------------------------------------------------------
// Kernel 0b: x [B][C][N] fp32 -> xT16 [B][N][C] bf16 (transpose + convert).
// 64x64 tiles via LDS. Grid (N/64, C/64, B), block 256.
// ---------------------------------------------------------------------------
__global__ __launch_bounds__(256) void xt_kernel(
    const float* __restrict__ x, u16* __restrict__ xT16)
{
    const int b = blockIdx.z, c0 = blockIdx.y * 64, n0 = blockIdx.x * 64;
    const int t = threadIdx.x;
    __shared__ float tile[64][65];

    const int cr = t >> 4, nc = (t & 15) * 4;
    #pragma unroll
    for (int it = 0; it < 4; ++it) {
        const float4 v = *(const float4*)(x + (size_t)(b * C_ + c0 + cr + it * 16) * N_ + n0 + nc);
        tile[cr + it * 16][nc + 0] = v.x; tile[cr + it * 16][nc + 1] = v.y;
        tile[cr + it * 16][nc + 2] = v.z; tile[cr + it * 16][nc + 3] = v.w;
    }
    __syncthreads();
    const int n = t >> 2, cg = (t & 3) * 16;
    union { u16 us[16]; uint4 u4[2]; } pk;
    #pragma unroll
    for (int e = 0; e < 16; ++e) pk.us[e] = f2bf(tile[cg + e][n]);
    uint4* dst = (uint4*)(xT16 + (size_t)(b * N_ + n0 + n) * C_ + c0 + cg);
    dst[0] = pk.u4[0]; dst[1] = pk.u4[1];
}

// ---------------------------------------------------------------------------
// Kernel 1: projections via MFMA.
//  thetaphi: A = xT16 (m=pixel), B = W16 rows 0..63 (n=o) -> D rows=n, cols=o
//            -> direct [n][32] stores for theta_t/phi_t.
//  g:        A = W16 rows 64..191 (m=c), B = xT16 (n=pixel) -> D rows=c
//            -> direct [c][n] stores for g16.
// Grid (N/64, B), block 256 (4 waves).
// ---------------------------------------------------------------------------
__global__ __launch_bounds__(256) void proj_mfma_kernel(
    const u16* __restrict__ xT16, const u16* __restrict__ W16,
    const float* __restrict__ theta_b, const float* __restrict__ phi_b,
    const float* __restrict__ g_b,
    u16* __restrict__ theta_t, u16* __restrict__ phi_t, u16* __restrict__ g16)
{
    const int b = blockIdx.y, n0 = blockIdx.x * 64;
    const int w = threadIdx.x >> 6, lane = threadIdx.x & 63;
    const int lr = lane & 15, q = lane >> 4;
    const f32x4 zf = {0.f, 0.f, 0.f, 0.f};

    // ---- theta/phi: wave w owns pixel m-tile w ----
    const u16* xrow = xT16 + (size_t)(b * N_ + n0 + w * 16 + lr) * C_;
    f32x4 acc[4];
    #pragma unroll
    for (int nt = 0; nt < 4; ++nt) acc[nt] = zf;
    for (int ks = 0; ks < 8; ++ks) {
        const short8 aX = *(const short8*)(xrow + ks * 32 + q * 8);
        #pragma unroll
        for (int nt = 0; nt < 4; ++nt) {
            const short8 bW = *(const short8*)(W16 + (size_t)(nt * 16 + lr) * C_ + ks * 32 + q * 8);
            acc[nt] = __builtin_amdgcn_mfma_f32_16x16x32_bf16(aX, bW, acc[nt], 0, 0, 0);
        }
    }
    #pragma unroll
    for (int nt = 0; nt < 4; ++nt) {
        const int o = nt * 16 + lr;
        #pragma unroll
        for (int reg = 0; reg < 4; ++reg) {
            const int n = n0 + w * 16 + q * 4 + reg;
            if (nt < 2)
                theta_t[(size_t)(b * N_ + n) * CK_ + o] = f2bf(acc[nt][reg] + theta_b[o] * LOG2E);
            else
                phi_t[(size_t)(b * N_ + n) * CK_ + (o - 32)] = f2bf(acc[nt][reg] + phi_b[o - 32]);
        }
    }

    // ---- g: wave w owns c m-tiles {2w, 2w+1}, processed sequentially ----
    #pragma unroll
    for (int mp = 0; mp < 2; ++mp) {
        const int crow = (w * 2 + mp) * 16;
        f32x4 ag[4];
        #pragma unroll
        for (int nt = 0; nt < 4; ++nt) ag[nt] = zf;
        for (int ks = 0; ks < 8; ++ks) {
            const short8 aW = *(const short8*)(W16 + (size_t)(64 + crow + lr) * C_ + ks * 32 + q * 8);
            #pragma unroll
            for (int nt = 0; nt < 4; ++nt) {
                const short8 bX = *(const short8*)(xT16 + (size_t)(b * N_ + n0 + nt * 16 + lr) * C_ + ks * 32 + q * 8);
                ag[nt] = __builtin_amdgcn_mfma_f32_16x16x32_bf16(aW, bX, ag[nt], 0, 0, 0);
            }
        }
        #pragma unroll
        for (int nt = 0; nt < 4; ++nt) {
            #pragma unroll
            for (int reg = 0; reg < 4; ++reg) {
                const int c = crow + q * 4 + reg;
                const int n = n0 + nt * 16 + lr;
                g16[(size_t)(b * CV_ + c) * N_ + n] = f2bf(ag[nt][reg] + g_b[c]);
            }
        }
    }
}

// ---------------------------------------------------------------------------
// Kernel 2: Z[b][j] = sum_i exp2(S[i][j]) via MFMA (unchanged from R2).
// ---------------------------------------------------------------------------
__global__ __launch_bounds__(256) void colstats_kernel(
    const u16* __restrict__ theta_t, const u16* __restrict__ phi_t,
    float* __restrict__ Z)
{
    const int b  = blockIdx.z;
    const int j0 = blockIdx.x * 32;
    const int istart = blockIdx.y * (N_ / 4);
    const int tid = threadIdx.x;
    const int wave = tid >> 6, lane = tid & 63;
    const int lr = lane & 15, q = lane >> 4;

    const int jW = j0 + (wave & 1) * 16;
    const short8 bF = *(const short8*)(phi_t + (size_t)(b * N_ + jW + lr) * CK_ + q * 8);

    const u16* thp = theta_t + (size_t)b * N_ * CK_;
    const f32x4 zero = {0.f, 0.f, 0.f, 0.f};
    float zacc = 0.f;
    for (int it = istart + (wave >> 1) * 16; it < istart + N_ / 4; it += 32) {
        const short8 aF = *(const short8*)(thp + (size_t)(it + lr) * CK_ + q * 8);
        f32x4 S = __builtin_amdgcn_mfma_f32_16x16x32_bf16(aF, bF, zero, 0, 0, 0);
        zacc += exp2f(S[0]) + exp2f(S[1]) + exp2f(S[2]) + exp2f(S[3]);
    }
    zacc += __shfl_xor(zacc, 16);
    zacc += __shfl_xor(zacc, 32);
    if (lane < 16) atomicAdd(&Z[(size_t)b * N_ + jW + lr], zacc);
}

// ---------------------------------------------------------------------------
// Kernel 3: fold 1/Z into g (in place, bf16). 8 elems/thread.
// ---------------------------------------------------------------------------
__global__ __launch_bounds__(256) void gscale_kernel(
    u16* __restrict__ g16, const float* __restrict__ Z)
{
    const size_t idx = ((size_t)blockIdx.x * 256 + threadIdx.x) * 8;
    const int n = (int)(idx & (N_ - 1));
    const int b = (int)(idx / ((size_t)CV_ * N_));
    uint4 raw = *(const uint4*)(g16 + idx);
    const float4 z0 = *(const float4*)(Z + (size_t)b * N_ + n);
    const float4 z1 = *(const float4*)(Z + (size_t)b * N_ + n + 4);
    const float zz[8] = {z0.x, z0.y, z0.z, z0.w, z1.x, z1.y, z1.z, z1.w};
    u16* pr = (u16*)&raw;
    union { u16 us[8]; uint4 u4; } pk;
    #pragma unroll
    for (int k = 0; k < 8; ++k) pk.us[k] = f2bf(bf2f(pr[k]) / zz[k]);
    *(uint4*)(g16 + idx) = pk.u4;
}

// ---------------------------------------------------------------------------
// Kernel 4: o_pre partial = sum_{j in half} gp[c][j] * exp2(S[i][j]).
// Grid (N/64, 2 j-halves, B) = 512 blocks, 512 threads (8 waves), 2 blk/CU.
// Double-buffered E -> ONE barrier per 64-j chunk; phi prefetched in regs.
// Wave w: S-tiles (i-tiles it2*2+{0,1}, j-tile w&3); PV c-strip w*16 x 64 i.
// Epilogue: LDS repack -> coalesced fp32 [n][cv] partial stores.
// ---------------------------------------------------------------------------
__global__ __launch_bounds__(512, 4) void opre_kernel(
    const u16* __restrict__ theta_t, const u16* __restrict__ phi_t,
    const u16* __restrict__ g16, float* __restrict__ o_p0, float* __restrict__ o_p1)
{
    const int b = blockIdx.z, jh = blockIdx.y, i0 = blockIdx.x * 64;
    const int w = threadIdx.x >> 6, lane = threadIdx.x & 63;
    const int lr = lane & 15, q = lane >> 4;

    __shared__ u16 El[2][64 * 64];      // 2 x 8 KB, XOR-swizzled 16B chunks
    __shared__ float rp[16 * 132];      // epilogue repack tile

    const int jt = w & 3, it2 = w >> 2;
    const short8 aF0 = *(const short8*)(theta_t + (size_t)(b * N_ + i0 + it2 * 32 + lr) * CK_ + q * 8);
    const short8 aF1 = *(const short8*)(theta_t + (size_t)(b * N_ + i0 + it2 * 32 + 16 + lr) * CK_ + q * 8);

    const int cw = w * 16;
    const u16* gb = g16 + (size_t)(b * CV_ + cw + lr) * N_;
    const u16* pb = phi_t + (size_t)(b * N_) * CK_;

    const f32x4 zf = {0.f, 0.f, 0.f, 0.f};
    f32x4 acc[4];
    #pragma unroll
    for (int nt = 0; nt < 4; ++nt) acc[nt] = zf;

    const int jstart = jh * (N_ / 2), jend = jstart + N_ / 2;
    short8 bF = *(const short8*)(pb + (size_t)(jstart + jt * 16 + lr) * CK_ + q * 8);
    int buf = 0;

    for (int j0 = jstart; j0 < jend; j0 += 64) {
        // g frags for this chunk (issue early; consumed after barrier)
        const short8 gA0 = *(const short8*)(gb + j0 + q * 8);
        const short8 gA1 = *(const short8*)(gb + j0 + 32 + q * 8);

        const f32x4 S0 = __builtin_amdgcn_mfma_f32_16x16x32_bf16(aF0, bF, zf, 0, 0, 0);
        const f32x4 S1 = __builtin_amdgcn_mfma_f32_16x16x32_bf16(aF1, bF, zf, 0, 0, 0);

        // prefetch next chunk's phi frag (register double-buffer)
        const int jn = (j0 + 64 < jend) ? j0 + 64 : jstart;
        bF = *(const short8*)(pb + (size_t)(jn + jt * 16 + lr) * CK_ + q * 8);

        // E = exp2(S) -> LDS (bf16), swizzled: phys chunk = (j>>3) ^ (i&7)
        u16* Eb = El[buf];
        const int jcol = jt * 16 + lr;
        #pragma unroll
        for (int reg = 0; reg < 4; ++reg) {
            const int ia = it2 * 32 + q * 4 + reg;
            Eb[ia * 64 + ((((jcol >> 3) ^ (ia & 7)) << 3) | (jcol & 7))] = f2bf(exp2f(S0[reg]));
            const int ib = ia + 16;
            Eb[ib * 64 + ((((jcol >> 3) ^ (ib & 7)) << 3) | (jcol & 7))] = f2bf(exp2f(S1[reg]));
        }
        __syncthreads();

        // PV: acc[nt] += gp . E^T  (B-frag: n=i, k=j)
        #pragma unroll
        for (int nt = 0; nt < 4; ++nt) {
            const int row = nt * 16 + lr;
            const short8 bE0 = *(const short8*)(Eb + row * 64 + ((q ^ (row & 7)) << 3));
            const short8 bE1 = *(const short8*)(Eb + row * 64 + (((4 + q) ^ (row & 7)) << 3));
            acc[nt] = __builtin_amdgcn_mfma_f32_16x16x32_bf16(gA0, bE0, acc[nt], 0, 0, 0);
            acc[nt] = __builtin_amdgcn_mfma_f32_16x16x32_bf16(gA1, bE1, acc[nt], 0, 0, 0);
        }
        buf ^= 1;
    }

    // epilogue: repack [c][i] acc -> coalesced [n][cv] fp32 partial stores
    __syncthreads();
    float* op = (jh ? o_p1 : o_p0) + (size_t)(b * N_ + i0) * CV_;
    #pragma unroll
    for (int p = 0; p < 4; ++p) {
        #pragma unroll
        for (int reg = 0; reg < 4; ++reg)
            rp[lr * 132 + cw + q * 4 + reg] = acc[p][reg];
        __syncthreads();
        const int t = threadIdx.x;
        const int ir = t >> 5, cc = (t & 31) * 4;
        *(float4*)(op + (size_t)(p * 16 + ir) * CV_ + cc) = *(const float4*)(rp + ir * 132 + cc);
        __syncthreads();
    }
}

// ---------------------------------------------------------------------------
// Kernel 5: out = x + gamma * (o_w @ (o_p0 + o_p1) + o_b) via MFMA.
// Grid (N/64, B), block 256 (4 waves). Wave w: oc m-tiles w*4..w*4+3.
// ---------------------------------------------------------------------------
__global__ __launch_bounds__(256) void final_mfma_kernel(
    const float* __restrict__ o_p0, const float* __restrict__ o_p1,
    const u16* __restrict__ ow16, const float* __restrict__ o_b,
    const float* __restrict__ gamma, const float* __restrict__ x,
    float* __restrict__ out)
{
    const int b = blockIdx.y, n0 = blockIdx.x * 64;
    const int w = threadIdx.x >> 6, lane = threadIdx.x & 63;
    const int lr = lane & 15, q = lane >> 4;
    const f32x4 zf = {0.f, 0.f, 0.f, 0.f};

    f32x4 acc[4][4];
    #pragma unroll
    for (int mt = 0; mt < 4; ++mt)
        #pragma unroll
        for (int nt = 0; nt < 4; ++nt) acc[mt][nt] = zf;

    const float* p0 = o_p0 + (size_t)(b * N_ + n0) * CV_;
    const float* p1 = o_p1 + (size_t)(b * N_ + n0) * CV_;

    for (int ks = 0; ks < 4; ++ks) {
        short8 bP[4];
        #pragma unroll
        for (int nt = 0; nt < 4; ++nt) {
            const size_t base = (size_t)(nt * 16 + lr) * CV_ + ks * 32 + q * 8;
            const float4 a0 = *(const float4*)(p0 + base);
            const float4 a1 = *(const float4*)(p0 + base + 4);
            const float4 b0 = *(const float4*)(p1 + base);
            const float4 b1 = *(const float4*)(p1 + base + 4);
            union { u16 us[8]; short8 s8; } pk;
            pk.us[0] = f2bf(a0.x + b0.x); pk.us[1] = f2bf(a0.y + b0.y);
            pk.us[2] = f2bf(a0.z + b0.z); pk.us[3] = f2bf(a0.w + b0.w);
            pk.us[4] = f2bf(a1.x + b1.x); pk.us[5] = f2bf(a1.y + b1.y);
            pk.us[6] = f2bf(a1.z + b1.z); pk.us[7] = f2bf(a1.w + b1.w);
            bP[nt] = pk.s8;
        }
        #pragma unroll
        for (int mt = 0; mt < 4; ++mt) {
            const short8 aW = *(const short8*)(ow16 + (size_t)((w * 4 + mt) * 16 + lr) * CV_ + ks * 32 + q * 8);
            #pragma unroll
            for (int nt = 0; nt < 4; ++nt)
                acc[mt][nt] = __builtin_amdgcn_mfma_f32_16x16x32_bf16(aW, bP[nt], acc[mt][nt], 0, 0, 0);
        }
    }

    const float gm = gamma[0];
    #pragma unroll
    for (int mt = 0; mt < 4; ++mt) {
        #pragma unroll
        for (int nt = 0; nt < 4; ++nt) {
            #pragma unroll
            for (int reg = 0; reg < 4; ++reg) {
                const int oc = (w * 4 + mt) * 16 + q * 4 + reg;
                const int n = n0 + nt * 16 + lr;
                const size_t off = (size_t)(b * C_ + oc) * N_ + n;
                out[off] = x[off] + gm * (acc[mt][nt][reg] + o_b[oc]);
            }
        }
    }
}

// ---------------------------------------------------------------------------
extern "C" void kernel_launch(void* const* d_in, const int* in_sizes, int n_in,
                              void* d_out, int out_size, void* d_ws, size_t ws_size,
                              hipStream_t stream)
{
    const float* x       = (const float*)d_in[0];
    const float* theta_w = (const float*)d_in[1];
    const float* theta_b = (const float*)d_in[2];
    const float* phi_w   = (const float*)d_in[3];
    const float* phi_b   = (const float*)d_in[4];
    const float* g_w     = (const float*)d_in[5];
    const float* g_b     = (const float*)d_in[6];
    const float* o_w     = (const float*)d_in[7];
    const float* o_b     = (const float*)d_in[8];
    const float* gamma   = (const float*)d_in[9];
    float* out = (float*)d_out;

    // workspace: xT16 8MB | W16 96KB | ow16 64KB | theta_t 1MB | phi_t 1MB |
    //            g16 4MB | Z 64KB | o_p0 8MB | o_p1 8MB   (~31 MB)
    u16* xT16    = (u16*)d_ws;
    u16* W16     = xT16 + (size_t)B_ * N_ * C_;
    u16* ow16    = W16 + 192 * C_;
    u16* theta_t = ow16 + C_ * CV_;
    u16* phi_t   = theta_t + (size_t)B_ * N_ * CK_;
    u16* g16     = phi_t + (size_t)B_ * N_ * CK_;
    float* Z     = (float*)(g16 + (size_t)B_ * CV_ * N_);
    float* o_p0  = Z + (size_t)B_ * N_;
    float* o_p1  = o_p0 + (size_t)B_ * N_ * CV_;

    hipMemsetAsync(Z, 0, (size_t)B_ * N_ * sizeof(float), stream);

    wconv_kernel<<<dim3(320), 256, 0, stream>>>(theta_w, phi_w, g_w, o_w, W16, ow16);
    xt_kernel<<<dim3(N_ / 64, C_ / 64, B_), 256, 0, stream>>>(x, xT16);
    proj_mfma_kernel<<<dim3(N_ / 64, B_), 256, 0, stream>>>(
        xT16, W16, theta_b, phi_b, g_b, theta_t, phi_t, g16);
    colstats_kernel<<<dim3(N_ / 32, 4, B_), 256, 0, stream>>>(theta_t, phi_t, Z);
    gscale_kernel<<<dim3((B_ * CV_ * N_) / 2048), 256, 0, stream>>>(g16, Z);
    opre_kernel<<<dim3(N_ / 64, 2, B_), 512, 0, stream>>>(theta_t, phi_t, g16, o_p0, o_p1);
    final_mfma_kernel<<<dim3(N_ / 64, B_), 256, 0, stream>>>(
        o_p0, o_p1, ow16, o_b, gamma, x, out);
}